// Round 1
// baseline (353.265 us; speedup 1.0000x reference)
//
#include <hip/hip_runtime.h>

#define H 64
#define NPIX 65536
#define LBATCH 8
#define LC 24
#define S_CHUNKS 32
#define INV_S2 2500.0f
#define EPSF 1e-6f

// grid sized exactly: LC*H*H/256 blocks
__global__ __launch_bounds__(256) void hist_zero(float* __restrict__ out) {
    const int i = blockIdx.x * 256 + threadIdx.x;
    out[i] = 0.0f;
}

// One block per (lc, pixel-chunk). 4 waves; each wave owns a full 64x64 fp32
// accumulator (lane = v column, acc index = u row). Broadcast-LDS A-row reads
// (same-address ds_read_b128 across all 64 lanes -> conflict-free broadcast).
__global__ __launch_bounds__(256, 3) void hist_main(const float* __restrict__ x,
                                                    float* __restrict__ out) {
    __shared__ float sU[4][64];
    __shared__ float sV[4][64];
    __shared__ float sW[4][64];
    __shared__ float sA[4][2][64];   // double-buffered A row per wave
    __shared__ float sHist[H * H];

    const int tid  = threadIdx.x;
    const int wv   = tid >> 6;
    const int lane = tid & 63;
    const int lc   = blockIdx.y;
    const int l    = lc / 3;
    const int c    = lc - 3 * l;

    #pragma unroll
    for (int r = 0; r < 16; r++) sHist[r * 256 + tid] = 0.0f;
    __syncthreads();

    const float offv = -3.0f + (6.0f / 63.0f) * (float)lane;

    const float* __restrict__ x0p = x + (l * 3 + 0) * NPIX;
    const float* __restrict__ x1p = x + (l * 3 + 1) * NPIX;
    const float* __restrict__ x2p = x + (l * 3 + 2) * NPIX;

    float acc[64];
    #pragma unroll
    for (int u = 0; u < 64; u++) acc[u] = 0.0f;

    const int PB   = NPIX / S_CHUNKS;        // 2048 pixels per block
    const int base = blockIdx.x * PB;

    for (int t = 0; t < PB / 256; t++) {     // 8 batches of 64 pixels per wave
        const int p = base + (t * 4 + wv) * 64 + lane;
        float v0 = x0p[p], v1 = x1p[p], v2 = x2p[p];
        v0 = fminf(fmaxf(v0, 0.0f), 1.0f);
        v1 = fminf(fmaxf(v1, 0.0f), 1.0f);
        v2 = fminf(fmaxf(v2, 0.0f), 1.0f);
        const float wgt = sqrtf(fmaf(v0, v0, fmaf(v1, v1, fmaf(v2, v2, EPSF))));
        const float lg0 = logf(v0 + EPSF);
        const float lg1 = logf(v1 + EPSF);
        const float lg2 = logf(v2 + EPSF);
        float U, V;
        if (c == 0)      { U = lg0 - lg1; V = lg0 - lg2; }
        else if (c == 1) { U = lg1 - lg0; V = lg1 - lg2; }
        else             { U = lg2 - lg0; V = lg2 - lg1; }
        // wave-private staging; same-wave LDS RAW is ordered by compiler waitcnts
        sU[wv][lane] = U;
        sV[wv][lane] = V;
        sW[wv][lane] = wgt;

        #pragma unroll 2
        for (int j = 0; j < 64; j++) {
            const float Uj = sU[wv][j];      // broadcast reads (uniform address)
            const float Vj = sV[wv][j];
            const float Wj = sW[wv][j];
            const float du = Uj - offv;      // lane = u for the A-row eval
            const float au = Wj * __builtin_amdgcn_rcpf(fmaf(du * du, INV_S2, 1.0f));
            sA[wv][j & 1][lane] = au;
            const float dv = Vj - offv;      // lane = v for the accumulator column
            const float kv = __builtin_amdgcn_rcpf(fmaf(dv * dv, INV_S2, 1.0f));
            const float4* __restrict__ av = (const float4*)(&sA[wv][j & 1][0]);
            #pragma unroll
            for (int q = 0; q < 16; q++) {   // 16x broadcast ds_read_b128
                const float4 a = av[q];
                acc[4 * q + 0] = fmaf(a.x, kv, acc[4 * q + 0]);
                acc[4 * q + 1] = fmaf(a.y, kv, acc[4 * q + 1]);
                acc[4 * q + 2] = fmaf(a.z, kv, acc[4 * q + 2]);
                acc[4 * q + 3] = fmaf(a.w, kv, acc[4 * q + 3]);
            }
        }
    }

    // merge the 4 wave accumulators into the block-level LDS histogram
    #pragma unroll
    for (int u = 0; u < 64; u++) atomicAdd(&sHist[u * 64 + lane], acc[u]);
    __syncthreads();

    float* __restrict__ g = out + lc * (H * H);
    #pragma unroll
    for (int r = 0; r < 16; r++) {
        const int i = r * 256 + tid;
        unsafeAtomicAdd(&g[i], sHist[i]);
    }
}

__global__ __launch_bounds__(256) void hist_total(const float* __restrict__ out,
                                                  float* __restrict__ tot) {
    const int l = blockIdx.x;
    const float* __restrict__ p = out + l * 3 * H * H;
    float s = 0.0f;
    for (int i = threadIdx.x; i < 3 * H * H; i += 256) s += p[i];
    #pragma unroll
    for (int off = 32; off > 0; off >>= 1) s += __shfl_down(s, off, 64);
    __shared__ float ps[4];
    if ((threadIdx.x & 63) == 0) ps[threadIdx.x >> 6] = s;
    __syncthreads();
    if (threadIdx.x == 0) tot[l] = (ps[0] + ps[1]) + (ps[2] + ps[3]);
}

__global__ __launch_bounds__(256) void hist_norm(float* __restrict__ out,
                                                 const float* __restrict__ tot) {
    const int i = blockIdx.x * 256 + threadIdx.x;
    const int l = i / (3 * H * H);
    out[i] = out[i] / (tot[l] + EPSF);
}

extern "C" void kernel_launch(void* const* d_in, const int* in_sizes, int n_in,
                              void* d_out, int out_size, void* d_ws, size_t ws_size,
                              hipStream_t stream) {
    const float* x = (const float*)d_in[0];
    float* out = (float*)d_out;
    float* tot = (float*)d_ws;   // 8 floats of scratch only

    hipLaunchKernelGGL(hist_zero,  dim3(LC * H * H / 256), dim3(256), 0, stream, out);
    hipLaunchKernelGGL(hist_main,  dim3(S_CHUNKS, LC),     dim3(256), 0, stream, x, out);
    hipLaunchKernelGGL(hist_total, dim3(LBATCH),           dim3(256), 0, stream, out, tot);
    hipLaunchKernelGGL(hist_norm,  dim3(LC * H * H / 256), dim3(256), 0, stream, out, tot);
}

// Round 2
// 168.617 us; speedup vs baseline: 2.0951x; 2.0951x over previous
//
#include <hip/hip_runtime.h>

#define H 64
#define NPIX 65536
#define LBATCH 8
#define LC 24
#define S_CHUNKS 32
#define EPSF 1e-6f

typedef _Float16 h8 __attribute__((ext_vector_type(8)));
typedef float f32x16 __attribute__((ext_vector_type(16)));

__global__ __launch_bounds__(256) void hist_zero(float* __restrict__ out) {
    out[blockIdx.x * 256 + threadIdx.x] = 0.0f;
}

// One block per (lc, pixel-chunk); 4 waves, each wave MFMA-accumulates the full
// 64x64 fp32 histogram for its own pixel subset. Per 64-pixel wave-iteration:
// cooperative pixel prep -> wave-private LDS; then 4 K-steps of 16 pixels, each
// evaluating fp16 A (=w*Ku) / B (=Kv) fragments in-register and issuing 4
// mfma_f32_32x32x16_f16. K-permutation invariance: A and B share the same
// pixel->k mapping, so only the measured C/D layout matters.
__global__ __launch_bounds__(256, 3) void hist_main(const float* __restrict__ x,
                                                    float* __restrict__ out) {
    __shared__ float sU[4][64];
    __shared__ float sV[4][64];
    __shared__ float sW[4][64];
    __shared__ float sHist[H * H];

    const int tid  = threadIdx.x;
    const int wv   = tid >> 6;
    const int lane = tid & 63;
    const int hf   = lane >> 5;      // which 32-lane half
    const int ln   = lane & 31;      // m/n index within a 32-tile
    const int lc   = blockIdx.y;
    const int l    = lc / 3;
    const int c    = lc - 3 * l;

    #pragma unroll
    for (int r = 0; r < 16; r++) sHist[r * 256 + tid] = 0.0f;
    __syncthreads();

    // offsets scaled by 50 (= 1/sigma): (50*(U-off))^2 == 2500*(U-off)^2
    const float step50 = 50.0f * (6.0f / 63.0f);
    const float ou0 = -150.0f + step50 * (float)ln;        // u/v tile 0
    const float ou1 = ou0 + step50 * 32.0f;                // u/v tile 1

    const float* __restrict__ x0p = x + (l * 3 + 0) * NPIX;
    const float* __restrict__ x1p = x + (l * 3 + 1) * NPIX;
    const float* __restrict__ x2p = x + (l * 3 + 2) * NPIX;

    f32x16 acc00, acc01, acc10, acc11;
    #pragma unroll
    for (int i = 0; i < 16; i++) { acc00[i] = 0.0f; acc01[i] = 0.0f; acc10[i] = 0.0f; acc11[i] = 0.0f; }

    const int PB   = NPIX / S_CHUNKS;        // 2048 pixels per block
    const int base = blockIdx.x * PB;

    for (int t = 0; t < PB / 256; t++) {     // 8 iterations of 64 px per wave
        const int p = base + (t * 4 + wv) * 64 + lane;
        float v0 = x0p[p], v1 = x1p[p], v2 = x2p[p];
        v0 = fminf(fmaxf(v0, 0.0f), 1.0f);
        v1 = fminf(fmaxf(v1, 0.0f), 1.0f);
        v2 = fminf(fmaxf(v2, 0.0f), 1.0f);
        const float wgt = sqrtf(fmaf(v0, v0, fmaf(v1, v1, fmaf(v2, v2, EPSF))));
        const float lg0 = logf(v0 + EPSF);
        const float lg1 = logf(v1 + EPSF);
        const float lg2 = logf(v2 + EPSF);
        float U, V;
        if (c == 0)      { U = lg0 - lg1; V = lg0 - lg2; }
        else if (c == 1) { U = lg1 - lg0; V = lg1 - lg2; }
        else             { U = lg2 - lg0; V = lg2 - lg1; }
        // wave-private staging (same-wave RAW ordered by compiler lgkmcnt)
        sU[wv][lane] = 50.0f * U;
        sV[wv][lane] = 50.0f * V;
        sW[wv][lane] = wgt;

        #pragma unroll
        for (int ks = 0; ks < 4; ks++) {     // 4 K-steps of 16 pixels
            const int pk = ks * 16 + hf * 8; // this half-wave's 8 k-pixels
            const float4 ua = *(const float4*)&sU[wv][pk];
            const float4 ub = *(const float4*)&sU[wv][pk + 4];
            const float4 va = *(const float4*)&sV[wv][pk];
            const float4 vb = *(const float4*)&sV[wv][pk + 4];
            const float4 wa = *(const float4*)&sW[wv][pk];
            const float4 wb = *(const float4*)&sW[wv][pk + 4];
            const float uu[8] = {ua.x, ua.y, ua.z, ua.w, ub.x, ub.y, ub.z, ub.w};
            const float vv[8] = {va.x, va.y, va.z, va.w, vb.x, vb.y, vb.z, vb.w};
            const float ww[8] = {wa.x, wa.y, wa.z, wa.w, wb.x, wb.y, wb.z, wb.w};
            h8 a0, a1, b0, b1;
            #pragma unroll
            for (int j = 0; j < 8; j++) {
                const float t0 = uu[j] - ou0;
                const float t1 = uu[j] - ou1;
                const float s0 = vv[j] - ou0;
                const float s1 = vv[j] - ou1;
                a0[j] = (_Float16)(ww[j] * __builtin_amdgcn_rcpf(fmaf(t0, t0, 1.0f)));
                a1[j] = (_Float16)(ww[j] * __builtin_amdgcn_rcpf(fmaf(t1, t1, 1.0f)));
                b0[j] = (_Float16)(__builtin_amdgcn_rcpf(fmaf(s0, s0, 1.0f)));
                b1[j] = (_Float16)(__builtin_amdgcn_rcpf(fmaf(s1, s1, 1.0f)));
            }
            acc00 = __builtin_amdgcn_mfma_f32_32x32x16_f16(a0, b0, acc00, 0, 0, 0);
            acc01 = __builtin_amdgcn_mfma_f32_32x32x16_f16(a0, b1, acc01, 0, 0, 0);
            acc10 = __builtin_amdgcn_mfma_f32_32x32x16_f16(a1, b0, acc10, 0, 0, 0);
            acc11 = __builtin_amdgcn_mfma_f32_32x32x16_f16(a1, b1, acc11, 0, 0, 0);
        }
    }

    // merge 4 wave accumulators (C/D layout: col=ln, row=(r&3)+8*(r>>2)+4*hf)
    #pragma unroll
    for (int r = 0; r < 16; r++) {
        const int row = (r & 3) + 8 * (r >> 2) + 4 * hf;
        atomicAdd(&sHist[row * 64 + ln],             acc00[r]);
        atomicAdd(&sHist[row * 64 + 32 + ln],        acc01[r]);
        atomicAdd(&sHist[(row + 32) * 64 + ln],      acc10[r]);
        atomicAdd(&sHist[(row + 32) * 64 + 32 + ln], acc11[r]);
    }
    __syncthreads();

    float* __restrict__ g = out + lc * (H * H);
    #pragma unroll
    for (int r = 0; r < 16; r++) {
        const int i = r * 256 + tid;
        unsafeAtomicAdd(&g[i], sHist[i]);
    }
}

// fused total + normalize: one block per sample l
__global__ __launch_bounds__(256) void hist_finish(float* __restrict__ out) {
    const int l = blockIdx.x;
    float* __restrict__ p = out + l * 3 * H * H;
    float s = 0.0f;
    for (int i = threadIdx.x; i < 3 * H * H; i += 256) s += p[i];
    #pragma unroll
    for (int off = 32; off > 0; off >>= 1) s += __shfl_down(s, off, 64);
    __shared__ float ps[4];
    if ((threadIdx.x & 63) == 0) ps[threadIdx.x >> 6] = s;
    __syncthreads();
    const float T = (ps[0] + ps[1]) + (ps[2] + ps[3]);
    const float inv = 1.0f / (T + EPSF);
    for (int i = threadIdx.x; i < 3 * H * H; i += 256) p[i] *= inv;
}

extern "C" void kernel_launch(void* const* d_in, const int* in_sizes, int n_in,
                              void* d_out, int out_size, void* d_ws, size_t ws_size,
                              hipStream_t stream) {
    const float* x = (const float*)d_in[0];
    float* out = (float*)d_out;

    hipLaunchKernelGGL(hist_zero,   dim3(LC * H * H / 256), dim3(256), 0, stream, out);
    hipLaunchKernelGGL(hist_main,   dim3(S_CHUNKS, LC),     dim3(256), 0, stream, x, out);
    hipLaunchKernelGGL(hist_finish, dim3(LBATCH),           dim3(256), 0, stream, out);
}

// Round 4
// 150.729 us; speedup vs baseline: 2.3437x; 1.1187x over previous
//
#include <hip/hip_runtime.h>

#define H 64
#define NPIX 65536
#define LBATCH 8
#define LC 24
#define S_CHUNKS 32
#define PB 2048            // pixels per block
#define EPSF 1e-6f
#define LN2_50 34.6573590f // 50 * ln(2): U50 = 50*(ln a - ln b) = LN2_50*(log2 a - log2 b)

typedef _Float16 h8 __attribute__((ext_vector_type(8)));   // MFMA operand view
typedef __fp16   g2 __attribute__((ext_vector_type(2)));   // cvt_pkrtz result view
typedef float f32x16 __attribute__((ext_vector_type(16)));
union H8u { h8 v8; g2 v2[4]; };                            // layout-identical pun

// inverse-quadratic RBF eval on pre-scaled coords: 1/(1+d^2)
#define KEV(d) __builtin_amdgcn_rcpf(fmaf((d), (d), 1.0f))
#define PK(a, b) __builtin_amdgcn_cvt_pkrtz((a), (b))

__global__ __launch_bounds__(256) void hist_zero(float* __restrict__ out) {
    out[blockIdx.x * 256 + threadIdx.x] = 0.0f;
}

// One block per (lc, 2048-pixel chunk). Phase 1: stage U50/V50/w for all 2048
// pixels into LDS (one barrier). Phase 2: each of 4 waves MFMA-accumulates the
// full 64x64 over its 512-pixel slice: 32 K-steps of (6 broadcast ds_read_b128
// -> 32 RBF evals -> 4 mfma_f32_32x32x16_f16). No global ops, no LDS
// write->read turnaround, no dynamic vector indexing (scratch-proof).
__global__ __launch_bounds__(256, 3) void hist_main(const float* __restrict__ x,
                                                    float* __restrict__ out) {
    __shared__ float sU[PB];
    __shared__ float sV[PB];
    __shared__ float sW[PB];
    __shared__ float sHist[H * H];

    const int tid  = threadIdx.x;
    const int wv   = tid >> 6;
    const int lane = tid & 63;
    const int hf   = lane >> 5;
    const int ln   = lane & 31;
    const int lc   = blockIdx.y;
    const int l    = lc / 3;
    const int c    = lc - 3 * l;

    // zero block histogram (float4 stores)
    #pragma unroll
    for (int r = 0; r < 4; r++)
        *(float4*)&sHist[(r * 256 + tid) * 4] = make_float4(0.f, 0.f, 0.f, 0.f);

    const float* __restrict__ x0p = x + (l * 3 + 0) * NPIX;
    const float* __restrict__ x1p = x + (l * 3 + 1) * NPIX;
    const float* __restrict__ x2p = x + (l * 3 + 2) * NPIX;
    const int base = blockIdx.x * PB;

    // ---- Phase 1: cooperative pixel prep (2 passes x 4 px/thread) ----
    #pragma unroll
    for (int pass = 0; pass < 2; pass++) {
        const int ploc = pass * 1024 + tid * 4;
        const float4 r0 = *(const float4*)&x0p[base + ploc];
        const float4 r1 = *(const float4*)&x1p[base + ploc];
        const float4 r2 = *(const float4*)&x2p[base + ploc];
        float4 U4, V4, W4;
        #define PREP(E) { \
            const float v0 = fminf(fmaxf(r0.E, 0.0f), 1.0f); \
            const float v1 = fminf(fmaxf(r1.E, 0.0f), 1.0f); \
            const float v2 = fminf(fmaxf(r2.E, 0.0f), 1.0f); \
            W4.E = __builtin_amdgcn_sqrtf(fmaf(v0, v0, fmaf(v1, v1, fmaf(v2, v2, EPSF)))); \
            const float lg0 = __builtin_amdgcn_logf(v0 + EPSF); \
            const float lg1 = __builtin_amdgcn_logf(v1 + EPSF); \
            const float lg2 = __builtin_amdgcn_logf(v2 + EPSF); \
            float U, V; \
            if (c == 0)      { U = lg0 - lg1; V = lg0 - lg2; } \
            else if (c == 1) { U = lg1 - lg0; V = lg1 - lg2; } \
            else             { U = lg2 - lg0; V = lg2 - lg1; } \
            U4.E = LN2_50 * U; V4.E = LN2_50 * V; }
        PREP(x) PREP(y) PREP(z) PREP(w)
        #undef PREP
        *(float4*)&sU[ploc] = U4;
        *(float4*)&sV[ploc] = V4;
        *(float4*)&sW[ploc] = W4;
    }
    __syncthreads();

    // ---- Phase 2: MFMA K-loop over this wave's 512-pixel slice ----
    const float step50 = 50.0f * (6.0f / 63.0f);
    const float ou0 = -150.0f + step50 * (float)ln;  // u/v bins [0,32)
    const float ou1 = ou0 + step50 * 32.0f;          // u/v bins [32,64)

    f32x16 acc00, acc01, acc10, acc11;
    #pragma unroll
    for (int i = 0; i < 16; i++) { acc00[i] = 0.f; acc01[i] = 0.f; acc10[i] = 0.f; acc11[i] = 0.f; }

    const int wbase = wv * 512;
    #pragma unroll 2
    for (int ks = 0; ks < 32; ks++) {
        const int kb = wbase + ks * 16 + hf * 8;     // half-wave's 8 k-pixels
        const float4 ua = *(const float4*)&sU[kb];
        const float4 ub = *(const float4*)&sU[kb + 4];
        const float4 va = *(const float4*)&sV[kb];
        const float4 vb = *(const float4*)&sV[kb + 4];
        const float4 wa = *(const float4*)&sW[kb];
        const float4 wb = *(const float4*)&sW[kb + 4];
        H8u A0, A1, B0, B1;
        A0.v2[0] = PK(wa.x * KEV(ua.x - ou0), wa.y * KEV(ua.y - ou0));
        A0.v2[1] = PK(wa.z * KEV(ua.z - ou0), wa.w * KEV(ua.w - ou0));
        A0.v2[2] = PK(wb.x * KEV(ub.x - ou0), wb.y * KEV(ub.y - ou0));
        A0.v2[3] = PK(wb.z * KEV(ub.z - ou0), wb.w * KEV(ub.w - ou0));
        A1.v2[0] = PK(wa.x * KEV(ua.x - ou1), wa.y * KEV(ua.y - ou1));
        A1.v2[1] = PK(wa.z * KEV(ua.z - ou1), wa.w * KEV(ua.w - ou1));
        A1.v2[2] = PK(wb.x * KEV(ub.x - ou1), wb.y * KEV(ub.y - ou1));
        A1.v2[3] = PK(wb.z * KEV(ub.z - ou1), wb.w * KEV(ub.w - ou1));
        B0.v2[0] = PK(KEV(va.x - ou0), KEV(va.y - ou0));
        B0.v2[1] = PK(KEV(va.z - ou0), KEV(va.w - ou0));
        B0.v2[2] = PK(KEV(vb.x - ou0), KEV(vb.y - ou0));
        B0.v2[3] = PK(KEV(vb.z - ou0), KEV(vb.w - ou0));
        B1.v2[0] = PK(KEV(va.x - ou1), KEV(va.y - ou1));
        B1.v2[1] = PK(KEV(va.z - ou1), KEV(va.w - ou1));
        B1.v2[2] = PK(KEV(vb.x - ou1), KEV(vb.y - ou1));
        B1.v2[3] = PK(KEV(vb.z - ou1), KEV(vb.w - ou1));
        acc00 = __builtin_amdgcn_mfma_f32_32x32x16_f16(A0.v8, B0.v8, acc00, 0, 0, 0);
        acc01 = __builtin_amdgcn_mfma_f32_32x32x16_f16(A0.v8, B1.v8, acc01, 0, 0, 0);
        acc10 = __builtin_amdgcn_mfma_f32_32x32x16_f16(A1.v8, B0.v8, acc10, 0, 0, 0);
        acc11 = __builtin_amdgcn_mfma_f32_32x32x16_f16(A1.v8, B1.v8, acc11, 0, 0, 0);
    }

    // merge 4 wave accumulators (C/D layout: col=ln, row=(r&3)+8*(r>>2)+4*hf)
    #pragma unroll
    for (int r = 0; r < 16; r++) {
        const int row = (r & 3) + 8 * (r >> 2) + 4 * hf;
        atomicAdd(&sHist[row * 64 + ln],             acc00[r]);
        atomicAdd(&sHist[row * 64 + 32 + ln],        acc01[r]);
        atomicAdd(&sHist[(row + 32) * 64 + ln],      acc10[r]);
        atomicAdd(&sHist[(row + 32) * 64 + 32 + ln], acc11[r]);
    }
    __syncthreads();

    float* __restrict__ g = out + lc * (H * H);
    #pragma unroll
    for (int r = 0; r < 16; r++) {
        const int i = r * 256 + tid;
        unsafeAtomicAdd(&g[i], sHist[i]);
    }
}

// fused total + normalize: one block per sample l
__global__ __launch_bounds__(256) void hist_finish(float* __restrict__ out) {
    const int l = blockIdx.x;
    float* __restrict__ p = out + l * 3 * H * H;
    float s = 0.0f;
    #pragma unroll
    for (int it = 0; it < 12; it++) {
        const float4 v = *(const float4*)&p[(it * 256 + threadIdx.x) * 4];
        s += (v.x + v.y) + (v.z + v.w);
    }
    #pragma unroll
    for (int off = 32; off > 0; off >>= 1) s += __shfl_down(s, off, 64);
    __shared__ float ps[4];
    if ((threadIdx.x & 63) == 0) ps[threadIdx.x >> 6] = s;
    __syncthreads();
    const float T = (ps[0] + ps[1]) + (ps[2] + ps[3]);
    const float inv = 1.0f / (T + EPSF);
    #pragma unroll
    for (int it = 0; it < 12; it++) {
        float4 v = *(const float4*)&p[(it * 256 + threadIdx.x) * 4];
        v.x *= inv; v.y *= inv; v.z *= inv; v.w *= inv;
        *(float4*)&p[(it * 256 + threadIdx.x) * 4] = v;
    }
}

extern "C" void kernel_launch(void* const* d_in, const int* in_sizes, int n_in,
                              void* d_out, int out_size, void* d_ws, size_t ws_size,
                              hipStream_t stream) {
    const float* x = (const float*)d_in[0];
    float* out = (float*)d_out;

    hipLaunchKernelGGL(hist_zero,   dim3(LC * H * H / 256), dim3(256), 0, stream, out);
    hipLaunchKernelGGL(hist_main,   dim3(S_CHUNKS, LC),     dim3(256), 0, stream, x, out);
    hipLaunchKernelGGL(hist_finish, dim3(LBATCH),           dim3(256), 0, stream, out);
}